// Round 1
// baseline (201.189 us; speedup 1.0000x reference)
//
#include <hip/hip_runtime.h>
#include <hip/hip_bf16.h>

// GraphSAGE fused kernels for MI355X (gfx950).
// N=768, NODE_IN=64, EDGE_IN=32, H=128, ROUNDS=2.
//
// Strategy: never materialize e / e_proj (302MB each). Per round, a fused
// kernel recomputes e_proj from edge_feats with bf16 MFMA and reduces over
// senders with adj weighting, one block per receiver j.

typedef __bf16 bf16x8 __attribute__((ext_vector_type(8)));
typedef float f32x4 __attribute__((ext_vector_type(4)));

#define NN   768
#define FEF  32
#define FH   128

static __device__ __forceinline__ unsigned short to_bf16u(float x) {
    return __builtin_bit_cast(unsigned short, (__bf16)x);
}

// ---------------------------------------------------------------- weight prep
// WeT[c][f] = bf16(We[f][c])   (128 x 32, k-minor for B-frags)
// Wa2T[c][k] = bf16(Wa[128+k][c]) (128 x 128, k-minor)
__global__ void k_wprep(const float* __restrict__ We, const float* __restrict__ Wa,
                        unsigned short* __restrict__ WeT, unsigned short* __restrict__ Wa2T) {
    int g = blockIdx.x * 256 + threadIdx.x;
    if (g < 128 * 32) {
        int c = g >> 5, f = g & 31;
        WeT[g] = to_bf16u(We[f * 128 + c]);
    }
    int g2 = g - 128 * 32;
    if (g2 >= 0 && g2 < 128 * 128) {
        int c = g2 >> 7, k = g2 & 127;
        Wa2T[g2] = to_bf16u(Wa[(128 + k) * 128 + c]);
    }
}

// ---------------------------------------------------------------- adj transpose
__global__ void k_transpose(const float* __restrict__ adj, float* __restrict__ adjT) {
    __shared__ float tile[32][33];
    int bx = blockIdx.x % 24, by = blockIdx.x / 24;
    int tx = threadIdx.x & 31, ty = threadIdx.x >> 5;  // 32 x 8
#pragma unroll
    for (int yy = 0; yy < 32; yy += 8)
        tile[ty + yy][tx] = adj[(size_t)(by * 32 + ty + yy) * NN + bx * 32 + tx];
    __syncthreads();
#pragma unroll
    for (int yy = 0; yy < 32; yy += 8)
        adjT[(size_t)(bx * 32 + ty + yy) * NN + by * 32 + tx] = tile[tx][ty + yy];
}

// ---------------------------------------------------------------- h0 = relu(nf@Wn+bn)
__global__ void k_h0(const float* __restrict__ nf, const float* __restrict__ Wn,
                     const float* __restrict__ bn, float* __restrict__ h) {
    __shared__ float nf_l[64];
    int i = blockIdx.x, t = threadIdx.x;
    if (t < 64) nf_l[t] = nf[i * 64 + t];
    __syncthreads();
    float acc = bn[t];
#pragma unroll 8
    for (int f = 0; f < 64; ++f) acc += nf_l[f] * Wn[f * 128 + t];
    h[i * 128 + t] = fmaxf(acc, 0.f);
}

// ---------------------------------------------------------------- spT[k][i] = (h@Wa1)[i][k] + ba[k]
__global__ void k_spT(const float* __restrict__ h, const float* __restrict__ Wa,
                      const float* __restrict__ ba, float* __restrict__ spT) {
    __shared__ float h_l[128];
    int i = blockIdx.x, t = threadIdx.x;
    h_l[t] = h[i * 128 + t];
    __syncthreads();
    float acc = ba[t];
#pragma unroll 8
    for (int f = 0; f < 128; ++f) acc += h_l[f] * Wa[f * 128 + t];
    spT[(size_t)t * NN + i] = acc;
}

// ---------------------------------------------------------------- the big fused kernel
// One block per receiver j. 4 waves in 2x2 (rows x cols of the 64x128 chunk tile).
__global__ __launch_bounds__(256, 2) void k_big(
    const float* __restrict__ ef, const float* __restrict__ adjT,
    const float* __restrict__ spT, const unsigned short* __restrict__ WeT,
    const unsigned short* __restrict__ Wa2T, const float* __restrict__ be,
    float* __restrict__ agg) {
    __shared__ unsigned short ef_lds[64 * 40];   // 64 rows x 32 bf16, padded stride 40 shorts (80B)
    __shared__ unsigned short E_lds[64 * 128];   // XOR-swizzled bf16
    __shared__ float adj_lds[NN];
    __shared__ float red[4][128];
    __shared__ float wred[4];
    __shared__ float s_invdeg;

    const int tid  = threadIdx.x;
    const int j    = blockIdx.x;
    const int lane = tid & 63;
    const int wave = tid >> 6;
    const int wr = wave >> 1, wc = wave & 1;
    const int lg = lane >> 4;    // k-group
    const int lr = lane & 15;    // row/col within 16-tile

    // stage adj column j (as row of adjT) + degree
    float asum = 0.f;
    for (int k = tid; k < NN; k += 256) {
        float a = adjT[(size_t)j * NN + k];
        adj_lds[k] = a;
        asum += a;
    }
#pragma unroll
    for (int off = 32; off; off >>= 1) asum += __shfl_down(asum, off);
    if (lane == 0) wred[wave] = asum;
    __syncthreads();
    if (tid == 0) {
        float d = wred[0] + wred[1] + wred[2] + wred[3];
        s_invdeg = 1.0f / fmaxf(d, 1.0f);
    }

    // hoist weight B-fragments into registers (constant across chunks)
    bf16x8 bwe[4];
    bf16x8 bwa[4][4];
    float bereg[4];
#pragma unroll
    for (int t = 0; t < 4; ++t) {
        int col = 64 * wc + 16 * t + lr;
        bwe[t] = *reinterpret_cast<const bf16x8*>(WeT + col * 32 + 8 * lg);
        bereg[t] = be[col];
#pragma unroll
        for (int s = 0; s < 4; ++s)
            bwa[t][s] = *reinterpret_cast<const bf16x8*>(Wa2T + col * 128 + 32 * s + 8 * lg);
    }

    float aggp[4] = {0.f, 0.f, 0.f, 0.f};
    const int r_st = tid >> 2;         // 0..63
    const int c_st = (tid & 3) * 8;    // 0,8,16,24

    for (int ic = 0; ic < 12; ++ic) {
        const int ibase = ic * 64;
        // ---- stage edge_feats[ibase..+63][j][:] -> bf16 LDS
        {
            const float* src = ef + (size_t)(ibase + r_st) * (NN * FEF) + j * FEF + c_st;
            float4 f0 = *reinterpret_cast<const float4*>(src);
            float4 f1 = *reinterpret_cast<const float4*>(src + 4);
            bf16x8 v;
            v[0] = (__bf16)f0.x; v[1] = (__bf16)f0.y; v[2] = (__bf16)f0.z; v[3] = (__bf16)f0.w;
            v[4] = (__bf16)f1.x; v[5] = (__bf16)f1.y; v[6] = (__bf16)f1.z; v[7] = (__bf16)f1.w;
            *reinterpret_cast<bf16x8*>(ef_lds + r_st * 40 + c_st) = v;
        }
        __syncthreads();

        // ---- GEMM1: E = relu(EF @ We + be), wave covers rows 32wr..+31, cols 64wc..+63
        f32x4 C1[2][4];
#pragma unroll
        for (int rt = 0; rt < 2; ++rt) {
            bf16x8 a = *reinterpret_cast<const bf16x8*>(ef_lds + (32 * wr + 16 * rt + lr) * 40 + 8 * lg);
#pragma unroll
            for (int t = 0; t < 4; ++t) {
                f32x4 c;
                c[0] = bereg[t]; c[1] = bereg[t]; c[2] = bereg[t]; c[3] = bereg[t];
                C1[rt][t] = __builtin_amdgcn_mfma_f32_16x16x32_bf16(a, bwe[t], c, 0, 0, 0);
            }
        }
        // write E to swizzled LDS (bf16)
#pragma unroll
        for (int rt = 0; rt < 2; ++rt)
#pragma unroll
            for (int t = 0; t < 4; ++t)
#pragma unroll
                for (int r = 0; r < 4; ++r) {
                    int grow = 32 * wr + 16 * rt + 4 * lg + r;
                    int gcol = 64 * wc + 16 * t + lr;
                    int idx = (grow * 128 + gcol) ^ ((grow & 7) << 3);
                    E_lds[idx] = to_bf16u(fmaxf(C1[rt][t][r], 0.f));
                }
        __syncthreads();

        // ---- GEMM2: P = E @ Wa2, C-init from spT (s_proj+ba), relu, adj-weight, accumulate
#pragma unroll
        for (int rt = 0; rt < 2; ++rt) {
            bf16x8 ae[4];
            int grow = 32 * wr + 16 * rt + lr;
#pragma unroll
            for (int s = 0; s < 4; ++s) {
                int off = (grow * 128 + 32 * s + 8 * lg) ^ ((grow & 7) << 3);
                ae[s] = *reinterpret_cast<const bf16x8*>(E_lds + off);
            }
            int i0 = ibase + 32 * wr + 16 * rt + 4 * lg;
            float av[4];
#pragma unroll
            for (int r = 0; r < 4; ++r) av[r] = adj_lds[i0 + r];
#pragma unroll
            for (int t = 0; t < 4; ++t) {
                int col = 64 * wc + 16 * t + lr;
                f32x4 C2 = *reinterpret_cast<const f32x4*>(spT + (size_t)col * NN + i0);
#pragma unroll
                for (int s = 0; s < 4; ++s)
                    C2 = __builtin_amdgcn_mfma_f32_16x16x32_bf16(ae[s], bwa[t][s], C2, 0, 0, 0);
#pragma unroll
                for (int r = 0; r < 4; ++r)
                    aggp[t] += fmaxf(C2[r], 0.f) * av[r];
            }
        }
        __syncthreads();
    }

    // reduce partials: lanes l, l+16, l+32, l+48 share a column
#pragma unroll
    for (int t = 0; t < 4; ++t) {
        float v = aggp[t];
        v += __shfl_xor(v, 16);
        v += __shfl_xor(v, 32);
        if (lane < 16) red[wave][64 * wc + 16 * t + lane] = v;
    }
    __syncthreads();
    if (tid < 128) {
        int col = tid, w = col >> 6;
        agg[(size_t)j * 128 + col] = (red[w][col] + red[w + 2][col]) * s_invdeg;
    }
}

// ---------------------------------------------------------------- h = relu([h,agg]@Wu + bu)
__global__ void k_update(float* __restrict__ h, const float* __restrict__ agg,
                         const float* __restrict__ Wu, const float* __restrict__ bu) {
    __shared__ float buf[256];
    int i = blockIdx.x, t = threadIdx.x;
    buf[t] = h[i * 128 + t];
    buf[128 + t] = agg[i * 128 + t];
    __syncthreads();
    float acc = bu[t];
#pragma unroll 8
    for (int f = 0; f < 256; ++f) acc += buf[f] * Wu[f * 128 + t];
    __syncthreads();
    h[i * 128 + t] = fmaxf(acc, 0.f);
}

// ---------------------------------------------------------------- outputs
__global__ void k_copy(const float* __restrict__ h, float* __restrict__ out) {
    int g = blockIdx.x * 256 + threadIdx.x;
    reinterpret_cast<float4*>(out)[g] = reinterpret_cast<const float4*>(h)[g];
}

__global__ void k_gemb(const float* __restrict__ h, float* __restrict__ out) {
    int c = blockIdx.x, l = threadIdx.x;
    float acc = 0.f;
    for (int i = l; i < NN; i += 64) acc += h[(size_t)i * 128 + c];
#pragma unroll
    for (int off = 32; off; off >>= 1) acc += __shfl_down(acc, off);
    if (l == 0) out[NN * 128 + c] = acc * (1.0f / 768.0f);
}

extern "C" void kernel_launch(void* const* d_in, const int* in_sizes, int n_in,
                              void* d_out, int out_size, void* d_ws, size_t ws_size,
                              hipStream_t stream) {
    const float* nf  = (const float*)d_in[0];
    const float* ef  = (const float*)d_in[1];
    const float* adj = (const float*)d_in[2];
    const float* Wn  = (const float*)d_in[3];
    const float* bn  = (const float*)d_in[4];
    const float* We  = (const float*)d_in[5];
    const float* be  = (const float*)d_in[6];
    const float* Wa  = (const float*)d_in[7];
    const float* ba  = (const float*)d_in[8];
    const float* Wu  = (const float*)d_in[9];
    const float* bu  = (const float*)d_in[10];
    float* out = (float*)d_out;

    // workspace carve-up (floats): h | agg | spT | adjT | WeT(bf16) | Wa2T(bf16)
    float* h_buf = (float*)d_ws;
    float* agg   = h_buf + NN * 128;
    float* spT   = agg + NN * 128;
    float* adjT  = spT + 128 * NN;
    unsigned short* WeT  = (unsigned short*)(adjT + NN * NN);
    unsigned short* Wa2T = WeT + 128 * 32;

    k_wprep<<<80, 256, 0, stream>>>(We, Wa, WeT, Wa2T);
    k_transpose<<<576, 256, 0, stream>>>(adj, adjT);
    k_h0<<<NN, 128, 0, stream>>>(nf, Wn, bn, h_buf);

    for (int r = 0; r < 2; ++r) {
        k_spT<<<NN, 128, 0, stream>>>(h_buf, Wa, ba, spT);
        k_big<<<NN, 256, 0, stream>>>(ef, adjT, spT, WeT, Wa2T, be, agg);
        k_update<<<NN, 128, 0, stream>>>(h_buf, agg, Wu, bu);
    }

    k_copy<<<NN * 128 / (256 * 4), 256, 0, stream>>>(h_buf, out);
    k_gemb<<<128, 64, 0, stream>>>(h_buf, out);
}